// Round 8
// baseline (411.086 us; speedup 1.0000x reference)
//
#include <hip/hip_runtime.h>
#include <hip/hip_bf16.h>
#include <stdint.h>

#define S_LEN 4096
#define D_MODEL 1024
#define N_HEADS 16
#define D_HEAD 64
#define SCALE_LOG2E 0.1803368787f   // (1/sqrt(64)) * log2(e)

typedef __attribute__((ext_vector_type(4))) float f32x4;
typedef __attribute__((ext_vector_type(8))) __bf16 bf16x8;
typedef __attribute__((ext_vector_type(4))) __bf16 bf16x4;

__device__ __forceinline__ unsigned short f2bf(float f) {
    union { float f; unsigned u; } x{f};
    unsigned r = x.u + 0x7fff + ((x.u >> 16) & 1);
    return (unsigned short)(r >> 16);
}

__device__ __forceinline__ void gld_lds16(const void* g, void* l) {
    __builtin_amdgcn_global_load_lds(
        (const __attribute__((address_space(1))) unsigned int*)g,
        (__attribute__((address_space(3))) unsigned int*)l, 16, 0, 0);
}

// ---------------- f32 -> bf16 convert ----------------
__global__ __launch_bounds__(256) void to_bf16_k(const float* __restrict__ src,
                                                 unsigned short* __restrict__ dst, int n) {
    int i = (blockIdx.x * 256 + threadIdx.x) * 4;
    if (i < n) {
        float4 v = *(const float4*)&src[i];
        ushort4 o;
        o.x = f2bf(v.x); o.y = f2bf(v.y); o.z = f2bf(v.z); o.w = f2bf(v.w);
        *(ushort4*)&dst[i] = o;
    }
}

// ---------------- RoPE cos/sin tables ----------------
__global__ __launch_bounds__(256) void rope_tables_k(const int* __restrict__ pos,
                                                     float* __restrict__ ct,
                                                     float* __restrict__ st) {
    int i = blockIdx.x * 256 + threadIdx.x;   // [0, 4096*32)
    int s = i >> 5, k = i & 31;
    float invf = __builtin_exp2f(-(float)(2 * k) * (1.0f / 64.0f) * 13.287712379549449f);
    float ang = (float)pos[s] * invf;
    ct[i] = cosf(ang);
    st[i] = sinf(ang);
}

// ---------------- V transpose: Vrow [S][1024] -> Vt [1024][S] ----------------
__global__ __launch_bounds__(256) void vtrans_k(const unsigned short* __restrict__ src,
                                                unsigned short* __restrict__ dst) {
    __shared__ unsigned short tile[64 * 68];
    const int bs = blockIdx.x * 64;   // s tile
    const int bd = blockIdx.y * 64;   // d tile
    const int t = threadIdx.x;
    {
        int col = (t & 7) * 8;
        #pragma unroll
        for (int rr = 0; rr < 2; ++rr) {
            int row = rr * 32 + (t >> 3);
            const unsigned short* g = src + (size_t)(bs + row) * D_MODEL + bd + col;
            ushort4 a = *(const ushort4*)g;
            ushort4 b = *(const ushort4*)(g + 4);
            *(ushort4*)&tile[row * 68 + col] = a;
            *(ushort4*)&tile[row * 68 + col + 4] = b;
        }
    }
    __syncthreads();
    {
        int dl = t >> 2;             // 0..63 d row
        int sc = (t & 3) * 16;       // s chunk
        ushort4 o[4];
        #pragma unroll
        for (int e = 0; e < 16; ++e)
            ((unsigned short*)o)[e] = tile[(sc + e) * 68 + dl];
        unsigned short* g = dst + (size_t)(bd + dl) * S_LEN + bs + sc;
        *(ushort4*)(g + 0)  = o[0];
        *(ushort4*)(g + 4)  = o[1];
        *(ushort4*)(g + 8)  = o[2];
        *(ushort4*)(g + 12) = o[3];
    }
}

// ---------------- NT GEMM: C[m,n] = sum_k A[m,k]*B[n,k] ----------------
// MODE 0: bf16 out; MODE 1: RoPE epilogue + scale + bf16 out; MODE 2: f32 out
template <int MODE>
__global__ __launch_bounds__(256) void gemm_nt_k(const unsigned short* __restrict__ A,
                                                 const unsigned short* __restrict__ B,
                                                 void* __restrict__ Cout,
                                                 int M, int N, int K,
                                                 const float* __restrict__ costab,
                                                 const float* __restrict__ sintab,
                                                 float scl) {
    __shared__ unsigned short lA[128 * 64];
    __shared__ unsigned short lB[128 * 64];
    const int t = threadIdx.x, w = t >> 6, l = t & 63;
    const int tm = blockIdx.y * 128, tn = blockIdx.x * 128;
    const int wm = (w >> 1) * 64, wn = (w & 1) * 64;
    const int g = l >> 4, ln = l & 15;

    f32x4 acc[4][4] = {};

    for (int k0 = 0; k0 < K; k0 += 64) {
        #pragma unroll
        for (int r = 0; r < 4; ++r) {
            int row = 8 * (4 * r + w) + (l >> 3);
            const unsigned short* ga = A + (size_t)(tm + row) * K + k0 + (l & 7) * 8;
            gld_lds16(ga, &lA[(4 * r + w) * 512]);
            const unsigned short* gb = B + (size_t)(tn + row) * K + k0 + (l & 7) * 8;
            gld_lds16(gb, &lB[(4 * r + w) * 512]);
        }
        asm volatile("s_waitcnt vmcnt(0)" ::: "memory");
        __syncthreads();

        #pragma unroll
        for (int kk = 0; kk < 2; ++kk) {
            bf16x8 af[4], bf[4];
            #pragma unroll
            for (int i = 0; i < 4; ++i) {
                af[i] = *(const bf16x8*)&lA[(wm + i * 16 + ln) * 64 + kk * 32 + g * 8];
                bf[i] = *(const bf16x8*)&lB[(wn + i * 16 + ln) * 64 + kk * 32 + g * 8];
            }
            #pragma unroll
            for (int i = 0; i < 4; ++i)
                #pragma unroll
                for (int j = 0; j < 4; ++j)
                    acc[i][j] = __builtin_amdgcn_mfma_f32_16x16x32_bf16(af[i], bf[j], acc[i][j], 0, 0, 0);
        }
        __syncthreads();
    }

    // epilogue
    #pragma unroll
    for (int i = 0; i < 4; ++i) {
        #pragma unroll
        for (int j = 0; j < 4; ++j) {
            int col = tn + wn + j * 16 + ln;
            #pragma unroll
            for (int r = 0; r < 4; ++r) {
                int row = tm + wm + i * 16 + g * 4 + r;
                float v = acc[i][j][r];
                if (MODE == 1) {
                    float p = __shfl_xor(v, 1, 64);
                    int dd = col & 63;
                    int kidx = dd >> 1;
                    float c = costab[row * 32 + kidx];
                    float s = sintab[row * 32 + kidx];
                    v = ((dd & 1) ? (s * p + c * v) : (c * v - s * p)) * scl;
                }
                if (MODE == 2)
                    ((float*)Cout)[(size_t)row * N + col] = v;
                else
                    ((unsigned short*)Cout)[(size_t)row * N + col] = f2bf(v);
            }
        }
    }
}

// ---------------- causal flash attention (barrier-free) ----------------
// grid: (16 heads, 64 qblocks of 64 rows). block: 256 thr = 4 waves,
// wave = 16 q rows, fully independent (no __syncthreads in the loop).
// K/V fragments read directly from global (L2/L3-resident; staging them in
// LDS forced 2 barrier+vmcnt(0) drains per tile = the R5/R6 latency wall).
// Only LDS use: per-wave-private P buffer (compiler-ordered, no barrier).
__global__ __launch_bounds__(256, 3) void attn_k(const unsigned short* __restrict__ Qb,
                                                 const unsigned short* __restrict__ Kb,
                                                 const unsigned short* __restrict__ Vt,
                                                 unsigned short* __restrict__ ctxb) {
    __shared__ unsigned short lP[4][16 * 64];   // per-wave P [q=16][k=64], swizzled

    const int t = threadIdx.x, w = t >> 6, l = t & 63;
    const int h = blockIdx.x;
    const int qb = (gridDim.y - 1) - blockIdx.y;   // heavy blocks first
    const int q0 = qb * 64 + w * 16;
    const int g = l >> 4, ln = l & 15;

    // Q fragments (B-operand for swapped QK^T; pre-scaled by scale*log2e)
    bf16x8 aq[2];
    #pragma unroll
    for (int kk = 0; kk < 2; ++kk)
        aq[kk] = *(const bf16x8*)&Qb[(size_t)(q0 + ln) * D_MODEL + h * 64 + kk * 32 + g * 8];

    f32x4 acc[4] = {};
    float rm = -INFINITY, rs = 0.0f;
    char* lpw = (char*)&lP[w][0];

    for (int kt = 0; kt <= qb; ++kt) {
        // ---- load K fragments direct from global: row=k, col=d ----
        const unsigned short* Kt = Kb + (size_t)(kt * 64) * D_MODEL + h * 64;
        bf16x8 ak[4][2];
        #pragma unroll
        for (int ct = 0; ct < 4; ++ct)
            #pragma unroll
            for (int kk = 0; kk < 2; ++kk)
                ak[ct][kk] = *(const bf16x8*)&Kt[(size_t)(ct * 16 + ln) * D_MODEL + kk * 32 + g * 8];

        // ---- S^T = K Q^T  (lane: q = ln; k = ct*16 + g*4 + r) ----
        float p[16];
        __builtin_amdgcn_s_setprio(1);
        #pragma unroll
        for (int ct = 0; ct < 4; ++ct) {
            f32x4 z = {};
            z = __builtin_amdgcn_mfma_f32_16x16x32_bf16(ak[ct][0], aq[0], z, 0, 0, 0);
            z = __builtin_amdgcn_mfma_f32_16x16x32_bf16(ak[ct][1], aq[1], z, 0, 0, 0);
            #pragma unroll
            for (int r = 0; r < 4; ++r) p[ct * 4 + r] = z[r];
        }
        __builtin_amdgcn_s_setprio(0);

        // ---- causal mask (diagonal tile only) ----
        if (kt == qb) {
            int qg = q0 + ln;
            #pragma unroll
            for (int ct = 0; ct < 4; ++ct)
                #pragma unroll
                for (int r = 0; r < 4; ++r)
                    if (kt * 64 + ct * 16 + g * 4 + r > qg) p[ct * 4 + r] = -INFINITY;
        }

        // ---- online softmax, exp2 domain, defer-max (THR=8) ----
        float pmax = fmaxf(p[0], p[1]);
        #pragma unroll
        for (int i = 2; i < 16; i += 2)
            pmax = fmaxf(fmaxf(pmax, p[i]), p[i + 1]);
        pmax = fmaxf(pmax, __shfl_xor(pmax, 16, 64));
        pmax = fmaxf(pmax, __shfl_xor(pmax, 32, 64));
        if (__any(pmax > rm + 8.0f)) {
            float mn = fmaxf(rm, pmax);
            float fac = __builtin_amdgcn_exp2f(rm - mn);
            rm = mn;
            rs *= fac;
            #pragma unroll
            for (int mb = 0; mb < 4; ++mb) {
                f32x4 a = acc[mb];
                #pragma unroll
                for (int r = 0; r < 4; ++r) a[r] *= fac;
                acc[mb] = a;
            }
        }
        float ps = 0.0f;
        #pragma unroll
        for (int i = 0; i < 16; ++i) {
            float e = __builtin_amdgcn_exp2f(p[i] - rm);   // bounded by 2^8
            p[i] = e;
            ps += e;
        }
        ps += __shfl_xor(ps, 16, 64);
        ps += __shfl_xor(ps, 32, 64);
        rs += ps;

        // ---- pack P (bf16) to per-wave-PRIVATE LDS (no barrier needed) ----
        #pragma unroll
        for (int ct = 0; ct < 4; ++ct) {
            bf16x4 pv;
            pv[0] = (__bf16)p[ct * 4 + 0];
            pv[1] = (__bf16)p[ct * 4 + 1];
            pv[2] = (__bf16)p[ct * 4 + 2];
            pv[3] = (__bf16)p[ct * 4 + 3];
            int off = (ln * 128 + ct * 32 + g * 8) ^ ((ln & 7) << 4);
            *(bf16x4*)(lpw + off) = pv;
        }

        // ---- load V^T fragments direct from global: row=d, col=k ----
        const unsigned short* Vth = Vt + (size_t)(h * 64) * S_LEN + kt * 64;
        bf16x8 av[4][2];
        #pragma unroll
        for (int mb = 0; mb < 4; ++mb)
            #pragma unroll
            for (int kc = 0; kc < 2; ++kc)
                av[mb][kc] = *(const bf16x8*)&Vth[(size_t)(mb * 16 + ln) * S_LEN + kc * 32 + g * 8];

        // ---- ctx^T += V^T P^T  (lane: q = ln; d = mb*16 + g*4 + r) ----
        bf16x8 bp[2];
        #pragma unroll
        for (int kc = 0; kc < 2; ++kc) {
            int poff = (ln * 128 + kc * 64 + g * 16) ^ ((ln & 7) << 4);
            bp[kc] = *(const bf16x8*)(lpw + poff);
        }
        __builtin_amdgcn_s_setprio(1);
        #pragma unroll
        for (int mb = 0; mb < 4; ++mb) {
            acc[mb] = __builtin_amdgcn_mfma_f32_16x16x32_bf16(av[mb][0], bp[0], acc[mb], 0, 0, 0);
            acc[mb] = __builtin_amdgcn_mfma_f32_16x16x32_bf16(av[mb][1], bp[1], acc[mb], 0, 0, 0);
        }
        __builtin_amdgcn_s_setprio(0);
    }

    // ---- write ctx (bf16), vectorized 8B stores ----
    float inv = 1.0f / rs;
    #pragma unroll
    for (int mb = 0; mb < 4; ++mb) {
        bf16x4 o;
        #pragma unroll
        for (int r = 0; r < 4; ++r) o[r] = (__bf16)(acc[mb][r] * inv);
        *(bf16x4*)&ctxb[(size_t)(q0 + ln) * D_MODEL + h * 64 + mb * 16 + g * 4] = o;
    }
}

// ---------------- host side ----------------
extern "C" void kernel_launch(void* const* d_in, const int* in_sizes, int n_in,
                              void* d_out, int out_size, void* d_ws, size_t ws_size,
                              hipStream_t stream) {
    const float* x  = (const float*)d_in[0];
    const float* Wq = (const float*)d_in[1];
    const float* Wk = (const float*)d_in[2];
    const float* Wv = (const float*)d_in[3];
    const float* Wo = (const float*)d_in[4];
    const int* tpos = (const int*)d_in[5];
    float* out = (float*)d_out;

    char* ws = (char*)d_ws;
    unsigned short* xb   = (unsigned short*)(ws + 0);            // 8 MB
    unsigned short* Wqb  = (unsigned short*)(ws + (8u << 20));   // 2 MB
    unsigned short* Wkb  = (unsigned short*)(ws + (10u << 20));  // 2 MB
    unsigned short* Wvb  = (unsigned short*)(ws + (12u << 20));  // 2 MB
    unsigned short* Wob  = (unsigned short*)(ws + (14u << 20));  // 2 MB
    unsigned short* Qbuf = (unsigned short*)(ws + (16u << 20));  // 8 MB
    unsigned short* Kbuf = (unsigned short*)(ws + (24u << 20));  // 8 MB
    unsigned short* Vtb  = (unsigned short*)(ws + (32u << 20));  // 8 MB
    unsigned short* ctxb = (unsigned short*)(ws + (40u << 20));  // 8 MB
    unsigned short* Vrow = ctxb;  // alias: Vrow dead before attn writes ctxb
    float* costab = (float*)(ws + (48u << 20));                  // 512 KB
    float* sintab = (float*)(ws + (48u << 20) + (512u << 10));   // 512 KB

    to_bf16_k<<<4096, 256, 0, stream>>>(x, xb, S_LEN * D_MODEL);
    to_bf16_k<<<1024, 256, 0, stream>>>(Wq, Wqb, D_MODEL * D_MODEL);
    to_bf16_k<<<1024, 256, 0, stream>>>(Wk, Wkb, D_MODEL * D_MODEL);
    to_bf16_k<<<1024, 256, 0, stream>>>(Wv, Wvb, D_MODEL * D_MODEL);
    to_bf16_k<<<1024, 256, 0, stream>>>(Wo, Wob, D_MODEL * D_MODEL);
    rope_tables_k<<<512, 256, 0, stream>>>(tpos, costab, sintab);

    dim3 gg(D_MODEL / 128, S_LEN / 128);   // (8, 32)
    // Q: RoPE + pre-scale by scale*log2e (attn uses exp2 domain)
    gemm_nt_k<1><<<gg, 256, 0, stream>>>(xb, Wqb, Qbuf, S_LEN, D_MODEL, D_MODEL,
                                         costab, sintab, SCALE_LOG2E);
    // K: RoPE only
    gemm_nt_k<1><<<gg, 256, 0, stream>>>(xb, Wkb, Kbuf, S_LEN, D_MODEL, D_MODEL,
                                         costab, sintab, 1.0f);
    // V: plain bf16, row-major (transposed next)
    gemm_nt_k<0><<<gg, 256, 0, stream>>>(xb, Wvb, Vrow, S_LEN, D_MODEL, D_MODEL,
                                         nullptr, nullptr, 1.0f);
    // V transpose: Vrow [S][1024] -> Vt [1024][S]
    vtrans_k<<<dim3(S_LEN / 64, D_MODEL / 64), 256, 0, stream>>>(Vrow, Vtb);

    attn_k<<<dim3(N_HEADS, S_LEN / 64), 256, 0, stream>>>(Qbuf, Kbuf, Vtb, ctxb);

    gemm_nt_k<2><<<gg, 256, 0, stream>>>(ctxb, Wob, out, S_LEN, D_MODEL, D_MODEL,
                                         nullptr, nullptr, 1.0f);
}

// Round 9
// 212.814 us; speedup vs baseline: 1.9317x; 1.9317x over previous
//
#include <hip/hip_runtime.h>
#include <hip/hip_bf16.h>
#include <stdint.h>

#define S_LEN 4096
#define D_MODEL 1024
#define N_HEADS 16
#define D_HEAD 64
#define SCALE_LOG2E 0.1803368787f   // (1/sqrt(64)) * log2(e)

typedef __attribute__((ext_vector_type(4))) float f32x4;
typedef __attribute__((ext_vector_type(8))) __bf16 bf16x8;
typedef __attribute__((ext_vector_type(4))) __bf16 bf16x4;

__device__ __forceinline__ unsigned short f2bf(float f) {
    union { float f; unsigned u; } x{f};
    unsigned r = x.u + 0x7fff + ((x.u >> 16) & 1);
    return (unsigned short)(r >> 16);
}

__device__ __forceinline__ void gld_lds16(const void* g, void* l) {
    __builtin_amdgcn_global_load_lds(
        (const __attribute__((address_space(1))) unsigned int*)g,
        (__attribute__((address_space(3))) unsigned int*)l, 16, 0, 0);
}

// ---------------- f32 -> bf16 convert ----------------
__global__ __launch_bounds__(256) void to_bf16_k(const float* __restrict__ src,
                                                 unsigned short* __restrict__ dst, int n) {
    int i = (blockIdx.x * 256 + threadIdx.x) * 4;
    if (i < n) {
        float4 v = *(const float4*)&src[i];
        ushort4 o;
        o.x = f2bf(v.x); o.y = f2bf(v.y); o.z = f2bf(v.z); o.w = f2bf(v.w);
        *(ushort4*)&dst[i] = o;
    }
}

// ---------------- RoPE cos/sin tables ----------------
__global__ __launch_bounds__(256) void rope_tables_k(const int* __restrict__ pos,
                                                     float* __restrict__ ct,
                                                     float* __restrict__ st) {
    int i = blockIdx.x * 256 + threadIdx.x;   // [0, 4096*32)
    int s = i >> 5, k = i & 31;
    float invf = __builtin_exp2f(-(float)(2 * k) * (1.0f / 64.0f) * 13.287712379549449f);
    float ang = (float)pos[s] * invf;
    ct[i] = cosf(ang);
    st[i] = sinf(ang);
}

// ---------------- V transpose: Vrow [S][1024] -> Vt [1024][S] ----------------
__global__ __launch_bounds__(256) void vtrans_k(const unsigned short* __restrict__ src,
                                                unsigned short* __restrict__ dst) {
    __shared__ unsigned short tile[64 * 68];
    const int bs = blockIdx.x * 64;   // s tile
    const int bd = blockIdx.y * 64;   // d tile
    const int t = threadIdx.x;
    {
        int col = (t & 7) * 8;
        #pragma unroll
        for (int rr = 0; rr < 2; ++rr) {
            int row = rr * 32 + (t >> 3);
            const unsigned short* g = src + (size_t)(bs + row) * D_MODEL + bd + col;
            ushort4 a = *(const ushort4*)g;
            ushort4 b = *(const ushort4*)(g + 4);
            *(ushort4*)&tile[row * 68 + col] = a;
            *(ushort4*)&tile[row * 68 + col + 4] = b;
        }
    }
    __syncthreads();
    {
        int dl = t >> 2;             // 0..63 d row
        int sc = (t & 3) * 16;       // s chunk
        ushort4 o[4];
        #pragma unroll
        for (int e = 0; e < 16; ++e)
            ((unsigned short*)o)[e] = tile[(sc + e) * 68 + dl];
        unsigned short* g = dst + (size_t)(bd + dl) * S_LEN + bs + sc;
        *(ushort4*)(g + 0)  = o[0];
        *(ushort4*)(g + 4)  = o[1];
        *(ushort4*)(g + 8)  = o[2];
        *(ushort4*)(g + 12) = o[3];
    }
}

// ---------------- NT GEMM: C[m,n] = sum_k A[m,k]*B[n,k] ----------------
// MODE 0: bf16 out; MODE 1: RoPE epilogue + scale + bf16 out; MODE 2: f32 out
template <int MODE>
__global__ __launch_bounds__(256) void gemm_nt_k(const unsigned short* __restrict__ A,
                                                 const unsigned short* __restrict__ B,
                                                 void* __restrict__ Cout,
                                                 int M, int N, int K,
                                                 const float* __restrict__ costab,
                                                 const float* __restrict__ sintab,
                                                 float scl) {
    __shared__ unsigned short lA[128 * 64];
    __shared__ unsigned short lB[128 * 64];
    const int t = threadIdx.x, w = t >> 6, l = t & 63;
    const int tm = blockIdx.y * 128, tn = blockIdx.x * 128;
    const int wm = (w >> 1) * 64, wn = (w & 1) * 64;
    const int g = l >> 4, ln = l & 15;

    f32x4 acc[4][4] = {};

    for (int k0 = 0; k0 < K; k0 += 64) {
        #pragma unroll
        for (int r = 0; r < 4; ++r) {
            int row = 8 * (4 * r + w) + (l >> 3);
            const unsigned short* ga = A + (size_t)(tm + row) * K + k0 + (l & 7) * 8;
            gld_lds16(ga, &lA[(4 * r + w) * 512]);
            const unsigned short* gb = B + (size_t)(tn + row) * K + k0 + (l & 7) * 8;
            gld_lds16(gb, &lB[(4 * r + w) * 512]);
        }
        asm volatile("s_waitcnt vmcnt(0)" ::: "memory");
        __syncthreads();

        #pragma unroll
        for (int kk = 0; kk < 2; ++kk) {
            bf16x8 af[4], bf[4];
            #pragma unroll
            for (int i = 0; i < 4; ++i) {
                af[i] = *(const bf16x8*)&lA[(wm + i * 16 + ln) * 64 + kk * 32 + g * 8];
                bf[i] = *(const bf16x8*)&lB[(wn + i * 16 + ln) * 64 + kk * 32 + g * 8];
            }
            #pragma unroll
            for (int i = 0; i < 4; ++i)
                #pragma unroll
                for (int j = 0; j < 4; ++j)
                    acc[i][j] = __builtin_amdgcn_mfma_f32_16x16x32_bf16(af[i], bf[j], acc[i][j], 0, 0, 0);
        }
        __syncthreads();
    }

    // epilogue
    #pragma unroll
    for (int i = 0; i < 4; ++i) {
        #pragma unroll
        for (int j = 0; j < 4; ++j) {
            int col = tn + wn + j * 16 + ln;
            #pragma unroll
            for (int r = 0; r < 4; ++r) {
                int row = tm + wm + i * 16 + g * 4 + r;
                float v = acc[i][j][r];
                if (MODE == 1) {
                    float p = __shfl_xor(v, 1, 64);
                    int dd = col & 63;
                    int kidx = dd >> 1;
                    float c = costab[row * 32 + kidx];
                    float s = sintab[row * 32 + kidx];
                    v = ((dd & 1) ? (s * p + c * v) : (c * v - s * p)) * scl;
                }
                if (MODE == 2)
                    ((float*)Cout)[(size_t)row * N + col] = v;
                else
                    ((unsigned short*)Cout)[(size_t)row * N + col] = f2bf(v);
            }
        }
    }
}

// ---------------- causal flash attention (swapped QK^T and PV) ----------------
// grid: (16 heads, 64 qblocks). block: 256 thr = 4 waves, wave = 16 q rows.
// ONE barrier per kv-tile (end of tile, protects the shared K/V dbuf). The
// P-pack -> PV LDS dependency is wave-private: compiler-ordered lgkmcnt, no
// barrier, so the tile t+1 prefetch stays in flight across QK^T+softmax+PV.
__device__ __forceinline__ void stage_tiles(const unsigned short* __restrict__ Kb,
                                            const unsigned short* __restrict__ Vt,
                                            unsigned short* lK, unsigned short* lV,
                                            int h, int kt, int w, int l) {
    for (int r2 = 0; r2 < 2; ++r2) {
        int row = r2 * 32 + w * 8 + (l >> 3);
        int chunk = (l & 7) ^ (l >> 3);   // source pre-swizzle (row&7 == l>>3)
        gld_lds16(Kb + (size_t)(kt * 64 + row) * D_MODEL + h * 64 + chunk * 8,
                  lK + r2 * 2048 + w * 512);
        gld_lds16(Vt + (size_t)(h * 64 + row) * S_LEN + kt * 64 + chunk * 8,
                  lV + r2 * 2048 + w * 512);
    }
}

__global__ __launch_bounds__(256) void attn_k(const unsigned short* __restrict__ Qb,
                                              const unsigned short* __restrict__ Kb,
                                              const unsigned short* __restrict__ Vt,
                                              unsigned short* __restrict__ ctxb) {
    __shared__ unsigned short lK[2][64 * 64];   // K tile [k][d], swizzled
    __shared__ unsigned short lV[2][64 * 64];   // V^T tile [d][k], swizzled
    __shared__ unsigned short lP[4][16 * 64];   // per-wave P [q][k], swizzled

    const int t = threadIdx.x, w = t >> 6, l = t & 63;
    const int h = blockIdx.x;
    const int qb = (gridDim.y - 1) - blockIdx.y;   // heavy blocks first
    const int q0 = qb * 64 + w * 16;
    const int g = l >> 4, ln = l & 15;

    // Q fragments (B-operand for swapped QK^T; pre-scaled by scale*log2e)
    bf16x8 aq[2];
    #pragma unroll
    for (int kk = 0; kk < 2; ++kk)
        aq[kk] = *(const bf16x8*)&Qb[(size_t)(q0 + ln) * D_MODEL + h * 64 + kk * 32 + g * 8];

    f32x4 acc[4] = {};
    float rm = -INFINITY, rs = 0.0f;
    char* lpw = (char*)&lP[w][0];

    stage_tiles(Kb, Vt, &lK[0][0], &lV[0][0], h, 0, w, l);
    asm volatile("s_waitcnt vmcnt(0)" ::: "memory");
    __syncthreads();

    int cur = 0;
    for (int kt = 0; kt <= qb; ++kt) {
        if (kt < qb)
            stage_tiles(Kb, Vt, &lK[cur ^ 1][0], &lV[cur ^ 1][0], h, kt + 1, w, l);

        // ---- S^T = K Q^T  (lane: q = ln; k = ct*16 + g*4 + r) ----
        float p[16];
        __builtin_amdgcn_s_setprio(1);
        #pragma unroll
        for (int ct = 0; ct < 4; ++ct) {
            f32x4 z = {};
            #pragma unroll
            for (int kk = 0; kk < 2; ++kk) {
                int row = ct * 16 + ln;
                int off = (row * 128 + kk * 64 + g * 16) ^ ((row & 7) << 4);
                bf16x8 ak = *(const bf16x8*)((const char*)&lK[cur][0] + off);
                z = __builtin_amdgcn_mfma_f32_16x16x32_bf16(ak, aq[kk], z, 0, 0, 0);
            }
            #pragma unroll
            for (int r = 0; r < 4; ++r) p[ct * 4 + r] = z[r];
        }
        __builtin_amdgcn_s_setprio(0);

        // ---- causal mask (diagonal tile only) ----
        if (kt == qb) {
            int qg = q0 + ln;
            #pragma unroll
            for (int ct = 0; ct < 4; ++ct)
                #pragma unroll
                for (int r = 0; r < 4; ++r)
                    if (kt * 64 + ct * 16 + g * 4 + r > qg) p[ct * 4 + r] = -INFINITY;
        }

        // ---- online softmax, exp2 domain, defer-max (THR=8) ----
        float pmax = fmaxf(p[0], p[1]);
        #pragma unroll
        for (int i = 2; i < 16; i += 2)
            pmax = fmaxf(fmaxf(pmax, p[i]), p[i + 1]);   // v_max3 chain
        pmax = fmaxf(pmax, __shfl_xor(pmax, 16, 64));
        pmax = fmaxf(pmax, __shfl_xor(pmax, 32, 64));
        if (__any(pmax > rm + 8.0f)) {
            float mn = fmaxf(rm, pmax);
            float fac = __builtin_amdgcn_exp2f(rm - mn);
            rm = mn;
            rs *= fac;
            #pragma unroll
            for (int mb = 0; mb < 4; ++mb) {
                f32x4 a = acc[mb];
                #pragma unroll
                for (int r = 0; r < 4; ++r) a[r] *= fac;
                acc[mb] = a;
            }
        }
        float ps = 0.0f;
        #pragma unroll
        for (int i = 0; i < 16; ++i) {
            float e = __builtin_amdgcn_exp2f(p[i] - rm);   // bounded by 2^8
            p[i] = e;
            ps += e;
        }
        ps += __shfl_xor(ps, 16, 64);
        ps += __shfl_xor(ps, 32, 64);
        rs += ps;

        // ---- pack P (bf16, native casts -> v_cvt_pk) to per-wave LDS ----
        // Wave-private buffer: compiler inserts the lgkmcnt ordering for the
        // write->read dependency below; no block barrier needed here.
        #pragma unroll
        for (int ct = 0; ct < 4; ++ct) {
            bf16x4 pv;
            pv[0] = (__bf16)p[ct * 4 + 0];
            pv[1] = (__bf16)p[ct * 4 + 1];
            pv[2] = (__bf16)p[ct * 4 + 2];
            pv[3] = (__bf16)p[ct * 4 + 3];
            int off = (ln * 128 + ct * 32 + g * 8) ^ ((ln & 7) << 4);
            *(bf16x4*)(lpw + off) = pv;
        }

        // ---- ctx^T += V^T P^T  (lane: q = ln; d = mb*16 + g*4 + r) ----
        __builtin_amdgcn_s_setprio(1);
        #pragma unroll
        for (int mb = 0; mb < 4; ++mb) {
            #pragma unroll
            for (int kc = 0; kc < 2; ++kc) {
                int vrow = mb * 16 + ln;
                int voff = (vrow * 128 + kc * 64 + g * 16) ^ ((vrow & 7) << 4);
                bf16x8 av = *(const bf16x8*)((const char*)&lV[cur][0] + voff);
                int poff = (ln * 128 + kc * 64 + g * 16) ^ ((ln & 7) << 4);
                bf16x8 bp = *(const bf16x8*)(lpw + poff);
                acc[mb] = __builtin_amdgcn_mfma_f32_16x16x32_bf16(av, bp, acc[mb], 0, 0, 0);
            }
        }
        __builtin_amdgcn_s_setprio(0);

        // end-of-tile: prefetch landed + all waves done with buffer cur
        asm volatile("s_waitcnt vmcnt(0)" ::: "memory");
        __syncthreads();
        cur ^= 1;
    }

    // ---- write ctx (bf16), vectorized 8B stores ----
    float inv = 1.0f / rs;
    #pragma unroll
    for (int mb = 0; mb < 4; ++mb) {
        bf16x4 o;
        #pragma unroll
        for (int r = 0; r < 4; ++r) o[r] = (__bf16)(acc[mb][r] * inv);
        *(bf16x4*)&ctxb[(size_t)(q0 + ln) * D_MODEL + h * 64 + mb * 16 + g * 4] = o;
    }
}

// ---------------- host side ----------------
extern "C" void kernel_launch(void* const* d_in, const int* in_sizes, int n_in,
                              void* d_out, int out_size, void* d_ws, size_t ws_size,
                              hipStream_t stream) {
    const float* x  = (const float*)d_in[0];
    const float* Wq = (const float*)d_in[1];
    const float* Wk = (const float*)d_in[2];
    const float* Wv = (const float*)d_in[3];
    const float* Wo = (const float*)d_in[4];
    const int* tpos = (const int*)d_in[5];
    float* out = (float*)d_out;

    char* ws = (char*)d_ws;
    unsigned short* xb   = (unsigned short*)(ws + 0);            // 8 MB
    unsigned short* Wqb  = (unsigned short*)(ws + (8u << 20));   // 2 MB
    unsigned short* Wkb  = (unsigned short*)(ws + (10u << 20));  // 2 MB
    unsigned short* Wvb  = (unsigned short*)(ws + (12u << 20));  // 2 MB
    unsigned short* Wob  = (unsigned short*)(ws + (14u << 20));  // 2 MB
    unsigned short* Qbuf = (unsigned short*)(ws + (16u << 20));  // 8 MB
    unsigned short* Kbuf = (unsigned short*)(ws + (24u << 20));  // 8 MB
    unsigned short* Vtb  = (unsigned short*)(ws + (32u << 20));  // 8 MB
    unsigned short* ctxb = (unsigned short*)(ws + (40u << 20));  // 8 MB
    unsigned short* Vrow = ctxb;  // alias: Vrow dead before attn writes ctxb
    float* costab = (float*)(ws + (48u << 20));                  // 512 KB
    float* sintab = (float*)(ws + (48u << 20) + (512u << 10));   // 512 KB

    to_bf16_k<<<4096, 256, 0, stream>>>(x, xb, S_LEN * D_MODEL);
    to_bf16_k<<<1024, 256, 0, stream>>>(Wq, Wqb, D_MODEL * D_MODEL);
    to_bf16_k<<<1024, 256, 0, stream>>>(Wk, Wkb, D_MODEL * D_MODEL);
    to_bf16_k<<<1024, 256, 0, stream>>>(Wv, Wvb, D_MODEL * D_MODEL);
    to_bf16_k<<<1024, 256, 0, stream>>>(Wo, Wob, D_MODEL * D_MODEL);
    rope_tables_k<<<512, 256, 0, stream>>>(tpos, costab, sintab);

    dim3 gg(D_MODEL / 128, S_LEN / 128);   // (8, 32)
    // Q: RoPE + pre-scale by scale*log2e (attn uses exp2 domain)
    gemm_nt_k<1><<<gg, 256, 0, stream>>>(xb, Wqb, Qbuf, S_LEN, D_MODEL, D_MODEL,
                                         costab, sintab, SCALE_LOG2E);
    // K: RoPE only
    gemm_nt_k<1><<<gg, 256, 0, stream>>>(xb, Wkb, Kbuf, S_LEN, D_MODEL, D_MODEL,
                                         costab, sintab, 1.0f);
    // V: plain bf16, row-major (transposed next)
    gemm_nt_k<0><<<gg, 256, 0, stream>>>(xb, Wvb, Vrow, S_LEN, D_MODEL, D_MODEL,
                                         nullptr, nullptr, 1.0f);
    // V transpose: Vrow [S][1024] -> Vt [1024][S]
    vtrans_k<<<dim3(S_LEN / 64, D_MODEL / 64), 256, 0, stream>>>(Vrow, Vtb);

    attn_k<<<dim3(N_HEADS, S_LEN / 64), 256, 0, stream>>>(Qbuf, Kbuf, Vtb, ctxb);

    gemm_nt_k<2><<<gg, 256, 0, stream>>>(ctxb, Wob, out, S_LEN, D_MODEL, D_MODEL,
                                         nullptr, nullptr, 1.0f);
}

// Round 10
// 199.030 us; speedup vs baseline: 2.0654x; 1.0693x over previous
//
#include <hip/hip_runtime.h>
#include <hip/hip_bf16.h>
#include <stdint.h>

#define S_LEN 4096
#define D_MODEL 1024
#define N_HEADS 16
#define D_HEAD 64
#define SCALE_LOG2E 0.1803368787f   // (1/sqrt(64)) * log2(e)

typedef __attribute__((ext_vector_type(4))) float f32x4;
typedef __attribute__((ext_vector_type(8))) __bf16 bf16x8;
typedef __attribute__((ext_vector_type(4))) __bf16 bf16x4;

__device__ __forceinline__ unsigned short f2bf(float f) {
    union { float f; unsigned u; } x{f};
    unsigned r = x.u + 0x7fff + ((x.u >> 16) & 1);
    return (unsigned short)(r >> 16);
}

__device__ __forceinline__ void gld_lds16(const void* g, void* l) {
    __builtin_amdgcn_global_load_lds(
        (const __attribute__((address_space(1))) unsigned int*)g,
        (__attribute__((address_space(3))) unsigned int*)l, 16, 0, 0);
}

// ---------------- f32 -> bf16 convert (x) ----------------
__global__ __launch_bounds__(256) void to_bf16_k(const float* __restrict__ src,
                                                 unsigned short* __restrict__ dst, int n) {
    int i = (blockIdx.x * 256 + threadIdx.x) * 4;
    if (i < n) {
        float4 v = *(const float4*)&src[i];
        ushort4 o;
        o.x = f2bf(v.x); o.y = f2bf(v.y); o.z = f2bf(v.z); o.w = f2bf(v.w);
        *(ushort4*)&dst[i] = o;
    }
}

// ---------------- fused 4-weight convert (dst regions contiguous) ----------------
__global__ __launch_bounds__(256) void wconv_k(const float* __restrict__ a,
                                               const float* __restrict__ b,
                                               const float* __restrict__ c,
                                               const float* __restrict__ d,
                                               unsigned short* __restrict__ dst) {
    int i = (blockIdx.x * 256 + threadIdx.x) * 4;   // over 4 x 1M elements
    int sel = i >> 20;
    int off = i & ((1 << 20) - 1);
    const float* src = (sel == 0) ? a : (sel == 1) ? b : (sel == 2) ? c : d;
    float4 v = *(const float4*)&src[off];
    ushort4 o;
    o.x = f2bf(v.x); o.y = f2bf(v.y); o.z = f2bf(v.z); o.w = f2bf(v.w);
    *(ushort4*)&dst[i] = o;
}

// ---------------- RoPE cos/sin tables ----------------
__global__ __launch_bounds__(256) void rope_tables_k(const int* __restrict__ pos,
                                                     float* __restrict__ ct,
                                                     float* __restrict__ st) {
    int i = blockIdx.x * 256 + threadIdx.x;   // [0, 4096*32)
    int s = i >> 5, k = i & 31;
    float invf = __builtin_exp2f(-(float)(2 * k) * (1.0f / 64.0f) * 13.287712379549449f);
    float ang = (float)pos[s] * invf;
    ct[i] = cosf(ang);
    st[i] = sinf(ang);
}

// ---------------- V transpose: Vrow [S][1024] -> Vt [1024][S] ----------------
__global__ __launch_bounds__(256) void vtrans_k(const unsigned short* __restrict__ src,
                                                unsigned short* __restrict__ dst) {
    __shared__ unsigned short tile[64 * 68];
    const int bs = blockIdx.x * 64;   // s tile
    const int bd = blockIdx.y * 64;   // d tile
    const int t = threadIdx.x;
    {
        int col = (t & 7) * 8;
        #pragma unroll
        for (int rr = 0; rr < 2; ++rr) {
            int row = rr * 32 + (t >> 3);
            const unsigned short* g = src + (size_t)(bs + row) * D_MODEL + bd + col;
            ushort4 a = *(const ushort4*)g;
            ushort4 b = *(const ushort4*)(g + 4);
            *(ushort4*)&tile[row * 68 + col] = a;
            *(ushort4*)&tile[row * 68 + col + 4] = b;
        }
    }
    __syncthreads();
    {
        int dl = t >> 2;             // 0..63 d row
        int sc = (t & 3) * 16;       // s chunk
        ushort4 o[4];
        #pragma unroll
        for (int e = 0; e < 16; ++e)
            ((unsigned short*)o)[e] = tile[(sc + e) * 68 + dl];
        unsigned short* g = dst + (size_t)(bd + dl) * S_LEN + bs + sc;
        *(ushort4*)(g + 0)  = o[0];
        *(ushort4*)(g + 4)  = o[1];
        *(ushort4*)(g + 8)  = o[2];
        *(ushort4*)(g + 12) = o[3];
    }
}

// ---------------- NT GEMM: C[m,n] = sum_k A[m,k]*B[n,k] ----------------
// MODE 0: bf16 out; MODE 1: RoPE epilogue + scale + bf16 out; MODE 2: f32 out
template <int MODE>
__global__ __launch_bounds__(256) void gemm_nt_k(const unsigned short* __restrict__ A,
                                                 const unsigned short* __restrict__ B,
                                                 void* __restrict__ Cout,
                                                 int M, int N, int K,
                                                 const float* __restrict__ costab,
                                                 const float* __restrict__ sintab,
                                                 float scl) {
    __shared__ unsigned short lA[128 * 64];
    __shared__ unsigned short lB[128 * 64];
    const int t = threadIdx.x, w = t >> 6, l = t & 63;
    const int tm = blockIdx.y * 128, tn = blockIdx.x * 128;
    const int wm = (w >> 1) * 64, wn = (w & 1) * 64;
    const int g = l >> 4, ln = l & 15;

    f32x4 acc[4][4] = {};

    for (int k0 = 0; k0 < K; k0 += 64) {
        #pragma unroll
        for (int r = 0; r < 4; ++r) {
            int row = 8 * (4 * r + w) + (l >> 3);
            const unsigned short* ga = A + (size_t)(tm + row) * K + k0 + (l & 7) * 8;
            gld_lds16(ga, &lA[(4 * r + w) * 512]);
            const unsigned short* gb = B + (size_t)(tn + row) * K + k0 + (l & 7) * 8;
            gld_lds16(gb, &lB[(4 * r + w) * 512]);
        }
        asm volatile("s_waitcnt vmcnt(0)" ::: "memory");
        __syncthreads();

        #pragma unroll
        for (int kk = 0; kk < 2; ++kk) {
            bf16x8 af[4], bf[4];
            #pragma unroll
            for (int i = 0; i < 4; ++i) {
                af[i] = *(const bf16x8*)&lA[(wm + i * 16 + ln) * 64 + kk * 32 + g * 8];
                bf[i] = *(const bf16x8*)&lB[(wn + i * 16 + ln) * 64 + kk * 32 + g * 8];
            }
            #pragma unroll
            for (int i = 0; i < 4; ++i)
                #pragma unroll
                for (int j = 0; j < 4; ++j)
                    acc[i][j] = __builtin_amdgcn_mfma_f32_16x16x32_bf16(af[i], bf[j], acc[i][j], 0, 0, 0);
        }
        __syncthreads();
    }

    // epilogue
    #pragma unroll
    for (int i = 0; i < 4; ++i) {
        #pragma unroll
        for (int j = 0; j < 4; ++j) {
            int col = tn + wn + j * 16 + ln;
            #pragma unroll
            for (int r = 0; r < 4; ++r) {
                int row = tm + wm + i * 16 + g * 4 + r;
                float v = acc[i][j][r];
                if (MODE == 1) {
                    float p = __shfl_xor(v, 1, 64);
                    int dd = col & 63;
                    int kidx = dd >> 1;
                    float c = costab[row * 32 + kidx];
                    float s = sintab[row * 32 + kidx];
                    v = ((dd & 1) ? (s * p + c * v) : (c * v - s * p)) * scl;
                }
                if (MODE == 2)
                    ((float*)Cout)[(size_t)row * N + col] = v;
                else
                    ((unsigned short*)Cout)[(size_t)row * N + col] = f2bf(v);
            }
        }
    }
}

// ---------------- causal flash attention, PAIRED q-tiles for load balance ----
// grid: (16 heads, 32 pairs). block: 512 thr = 8 waves. Waves 0-3 own q-tile
// qA=blockIdx.y, waves 4-7 own qB=63-qA -> every block computes exactly 65
// kv-tile passes (uniform). Both tiles share the staged K/V for kt<=qA.
// ONE barrier per kv-tile; P buffer is wave-private (compiler-ordered).
__device__ __forceinline__ void stage8(const unsigned short* __restrict__ Kb,
                                       const unsigned short* __restrict__ Vt,
                                       unsigned short* lK, unsigned short* lV,
                                       int h, int kt, int w, int l) {
    const int half = w & 3;
    const int chunk = (l & 7) ^ (l >> 3);   // source pre-swizzle (row&7 == l>>3)
    if (w < 4) {
        #pragma unroll
        for (int r2 = 0; r2 < 2; ++r2) {
            int row = half * 16 + r2 * 8 + (l >> 3);
            gld_lds16(Kb + (size_t)(kt * 64 + row) * D_MODEL + h * 64 + chunk * 8,
                      lK + half * 1024 + r2 * 512);
        }
    } else {
        #pragma unroll
        for (int r2 = 0; r2 < 2; ++r2) {
            int row = half * 16 + r2 * 8 + (l >> 3);
            gld_lds16(Vt + (size_t)(h * 64 + row) * S_LEN + kt * 64 + chunk * 8,
                      lV + half * 1024 + r2 * 512);
        }
    }
}

__global__ __launch_bounds__(512) void attn_k(const unsigned short* __restrict__ Qb,
                                              const unsigned short* __restrict__ Kb,
                                              const unsigned short* __restrict__ Vt,
                                              unsigned short* __restrict__ ctxb) {
    __shared__ unsigned short lK[2][64 * 64];   // K tile [k][d], swizzled   16 KB
    __shared__ unsigned short lV[2][64 * 64];   // V^T tile [d][k], swizzled 16 KB
    __shared__ unsigned short lP[8][16 * 64];   // per-wave P [q][k]         16 KB

    const int t = threadIdx.x, w = t >> 6, l = t & 63;
    const int wv = w & 3;                   // sub-wave within tile
    const int sel = w >> 2;                 // 0 -> qA, 1 -> qB
    const int h = blockIdx.x;
    const int qA = blockIdx.y;              // 0..31
    const int qB = 63 - qA;                 // 32..63
    const int qT = sel ? qB : qA;
    const int q0 = qT * 64 + wv * 16;
    const int g = l >> 4, ln = l & 15;

    // Q fragments (B-operand for swapped QK^T; pre-scaled by scale*log2e)
    bf16x8 aq[2];
    #pragma unroll
    for (int kk = 0; kk < 2; ++kk)
        aq[kk] = *(const bf16x8*)&Qb[(size_t)(q0 + ln) * D_MODEL + h * 64 + kk * 32 + g * 8];

    f32x4 acc[4] = {};
    float rm = -INFINITY, rs = 0.0f;
    char* lpw = (char*)&lP[w][0];

    stage8(Kb, Vt, &lK[0][0], &lV[0][0], h, 0, w, l);
    asm volatile("s_waitcnt vmcnt(0)" ::: "memory");
    __syncthreads();

    int cur = 0;
    for (int kt = 0; kt <= qB; ++kt) {
        if (kt < qB)
            stage8(Kb, Vt, &lK[cur ^ 1][0], &lV[cur ^ 1][0], h, kt + 1, w, l);

        if (kt <= qT) {   // wave-uniform: this wave's q-tile still has kv left
            // ---- S^T = K Q^T  (lane: q = ln; k = ct*16 + g*4 + r) ----
            float p[16];
            __builtin_amdgcn_s_setprio(1);
            #pragma unroll
            for (int ct = 0; ct < 4; ++ct) {
                f32x4 z = {};
                #pragma unroll
                for (int kk = 0; kk < 2; ++kk) {
                    int row = ct * 16 + ln;
                    int off = (row * 128 + kk * 64 + g * 16) ^ ((row & 7) << 4);
                    bf16x8 ak = *(const bf16x8*)((const char*)&lK[cur][0] + off);
                    z = __builtin_amdgcn_mfma_f32_16x16x32_bf16(ak, aq[kk], z, 0, 0, 0);
                }
                #pragma unroll
                for (int r = 0; r < 4; ++r) p[ct * 4 + r] = z[r];
            }
            __builtin_amdgcn_s_setprio(0);

            // ---- causal mask (diagonal tile only) ----
            if (kt == qT) {
                int qg = q0 + ln;
                #pragma unroll
                for (int ct = 0; ct < 4; ++ct)
                    #pragma unroll
                    for (int r = 0; r < 4; ++r)
                        if (kt * 64 + ct * 16 + g * 4 + r > qg) p[ct * 4 + r] = -INFINITY;
            }

            // ---- online softmax, exp2 domain, defer-max (THR=8) ----
            float pmax = fmaxf(p[0], p[1]);
            #pragma unroll
            for (int i = 2; i < 16; i += 2)
                pmax = fmaxf(fmaxf(pmax, p[i]), p[i + 1]);
            pmax = fmaxf(pmax, __shfl_xor(pmax, 16, 64));
            pmax = fmaxf(pmax, __shfl_xor(pmax, 32, 64));
            if (__any(pmax > rm + 8.0f)) {
                float mn = fmaxf(rm, pmax);
                float fac = __builtin_amdgcn_exp2f(rm - mn);
                rm = mn;
                rs *= fac;
                #pragma unroll
                for (int mb = 0; mb < 4; ++mb) {
                    f32x4 a = acc[mb];
                    #pragma unroll
                    for (int r = 0; r < 4; ++r) a[r] *= fac;
                    acc[mb] = a;
                }
            }
            float ps = 0.0f;
            #pragma unroll
            for (int i = 0; i < 16; ++i) {
                float e = __builtin_amdgcn_exp2f(p[i] - rm);   // bounded by 2^8
                p[i] = e;
                ps += e;
            }
            ps += __shfl_xor(ps, 16, 64);
            ps += __shfl_xor(ps, 32, 64);
            rs += ps;

            // ---- pack P (bf16) to wave-private LDS (compiler-ordered) ----
            #pragma unroll
            for (int ct = 0; ct < 4; ++ct) {
                bf16x4 pv;
                pv[0] = (__bf16)p[ct * 4 + 0];
                pv[1] = (__bf16)p[ct * 4 + 1];
                pv[2] = (__bf16)p[ct * 4 + 2];
                pv[3] = (__bf16)p[ct * 4 + 3];
                int off = (ln * 128 + ct * 32 + g * 8) ^ ((ln & 7) << 4);
                *(bf16x4*)(lpw + off) = pv;
            }

            // ---- ctx^T += V^T P^T  (lane: q = ln; d = mb*16 + g*4 + r) ----
            __builtin_amdgcn_s_setprio(1);
            #pragma unroll
            for (int mb = 0; mb < 4; ++mb) {
                #pragma unroll
                for (int kc = 0; kc < 2; ++kc) {
                    int vrow = mb * 16 + ln;
                    int voff = (vrow * 128 + kc * 64 + g * 16) ^ ((vrow & 7) << 4);
                    bf16x8 av = *(const bf16x8*)((const char*)&lV[cur][0] + voff);
                    int poff = (ln * 128 + kc * 64 + g * 16) ^ ((ln & 7) << 4);
                    bf16x8 bp = *(const bf16x8*)(lpw + poff);
                    acc[mb] = __builtin_amdgcn_mfma_f32_16x16x32_bf16(av, bp, acc[mb], 0, 0, 0);
                }
            }
            __builtin_amdgcn_s_setprio(0);
        }

        // end-of-tile: prefetch landed + all waves done with buffer cur
        asm volatile("s_waitcnt vmcnt(0)" ::: "memory");
        __syncthreads();
        cur ^= 1;
    }

    // ---- write ctx (bf16), vectorized 8B stores ----
    float inv = 1.0f / rs;
    #pragma unroll
    for (int mb = 0; mb < 4; ++mb) {
        bf16x4 o;
        #pragma unroll
        for (int r = 0; r < 4; ++r) o[r] = (__bf16)(acc[mb][r] * inv);
        *(bf16x4*)&ctxb[(size_t)(q0 + ln) * D_MODEL + h * 64 + mb * 16 + g * 4] = o;
    }
}

// ---------------- host side ----------------
extern "C" void kernel_launch(void* const* d_in, const int* in_sizes, int n_in,
                              void* d_out, int out_size, void* d_ws, size_t ws_size,
                              hipStream_t stream) {
    const float* x  = (const float*)d_in[0];
    const float* Wq = (const float*)d_in[1];
    const float* Wk = (const float*)d_in[2];
    const float* Wv = (const float*)d_in[3];
    const float* Wo = (const float*)d_in[4];
    const int* tpos = (const int*)d_in[5];
    float* out = (float*)d_out;

    char* ws = (char*)d_ws;
    unsigned short* xb   = (unsigned short*)(ws + 0);            // 8 MB
    unsigned short* Wqb  = (unsigned short*)(ws + (8u << 20));   // 2 MB
    unsigned short* Wkb  = (unsigned short*)(ws + (10u << 20));  // 2 MB
    unsigned short* Wvb  = (unsigned short*)(ws + (12u << 20));  // 2 MB
    unsigned short* Wob  = (unsigned short*)(ws + (14u << 20));  // 2 MB
    unsigned short* Qbuf = (unsigned short*)(ws + (16u << 20));  // 8 MB
    unsigned short* Kbuf = (unsigned short*)(ws + (24u << 20));  // 8 MB
    unsigned short* Vtb  = (unsigned short*)(ws + (32u << 20));  // 8 MB
    unsigned short* ctxb = (unsigned short*)(ws + (40u << 20));  // 8 MB
    unsigned short* Vrow = ctxb;  // alias: Vrow dead before attn writes ctxb
    float* costab = (float*)(ws + (48u << 20));                  // 512 KB
    float* sintab = (float*)(ws + (48u << 20) + (512u << 10));   // 512 KB

    to_bf16_k<<<4096, 256, 0, stream>>>(x, xb, S_LEN * D_MODEL);
    wconv_k<<<4096, 256, 0, stream>>>(Wq, Wk, Wv, Wo, Wqb);  // Wqb..Wob contiguous
    rope_tables_k<<<512, 256, 0, stream>>>(tpos, costab, sintab);

    dim3 gg(D_MODEL / 128, S_LEN / 128);   // (8, 32)
    // Q: RoPE + pre-scale by scale*log2e (attn uses exp2 domain)
    gemm_nt_k<1><<<gg, 256, 0, stream>>>(xb, Wqb, Qbuf, S_LEN, D_MODEL, D_MODEL,
                                         costab, sintab, SCALE_LOG2E);
    // K: RoPE only
    gemm_nt_k<1><<<gg, 256, 0, stream>>>(xb, Wkb, Kbuf, S_LEN, D_MODEL, D_MODEL,
                                         costab, sintab, 1.0f);
    // V: plain bf16, row-major (transposed next)
    gemm_nt_k<0><<<gg, 256, 0, stream>>>(xb, Wvb, Vrow, S_LEN, D_MODEL, D_MODEL,
                                         nullptr, nullptr, 1.0f);
    // V transpose: Vrow [S][1024] -> Vt [1024][S]
    vtrans_k<<<dim3(S_LEN / 64, D_MODEL / 64), 256, 0, stream>>>(Vrow, Vtb);

    // paired causal attention: 32 balanced blocks per head
    attn_k<<<dim3(N_HEADS, 32), 512, 0, stream>>>(Qbuf, Kbuf, Vtb, ctxb);

    gemm_nt_k<2><<<gg, 256, 0, stream>>>(ctxb, Wob, out, S_LEN, D_MODEL, D_MODEL,
                                         nullptr, nullptr, 1.0f);
}

// Round 11
// 165.326 us; speedup vs baseline: 2.4865x; 1.2039x over previous
//
#include <hip/hip_runtime.h>
#include <hip/hip_bf16.h>
#include <stdint.h>

#define S_LEN 4096
#define D_MODEL 1024
#define N_HEADS 16
#define D_HEAD 64
#define LDQKV 3072
#define SCALE_LOG2E 0.1803368787f   // (1/sqrt(64)) * log2(e)

typedef __attribute__((ext_vector_type(4))) float f32x4;
typedef __attribute__((ext_vector_type(8))) __bf16 bf16x8;
typedef __attribute__((ext_vector_type(4))) __bf16 bf16x4;

__device__ __forceinline__ unsigned short f2bf(float f) {
    union { float f; unsigned u; } x{f};
    unsigned r = x.u + 0x7fff + ((x.u >> 16) & 1);
    return (unsigned short)(r >> 16);
}

__device__ __forceinline__ void gld_lds16(const void* g, void* l) {
    __builtin_amdgcn_global_load_lds(
        (const __attribute__((address_space(1))) unsigned int*)g,
        (__attribute__((address_space(3))) unsigned int*)l, 16, 0, 0);
}

// ---------------- fused prep: x->bf16, weights->bf16, RoPE tables ----------------
// grid: 4096 (x) + 4096 (weights) + 1024 (tables) = 9216 blocks x 256
__global__ __launch_bounds__(256) void prep_k(const float* __restrict__ x,
                                              const float* __restrict__ Wq,
                                              const float* __restrict__ Wk,
                                              const float* __restrict__ Wv,
                                              const float* __restrict__ Wo,
                                              const int* __restrict__ pos,
                                              unsigned short* __restrict__ xb,
                                              unsigned short* __restrict__ Wb,
                                              float* __restrict__ ct,
                                              float* __restrict__ st) {
    int b = blockIdx.x;
    if (b < 4096) {
        int i = (b * 256 + threadIdx.x) * 4;
        float4 v = *(const float4*)&x[i];
        ushort4 o;
        o.x = f2bf(v.x); o.y = f2bf(v.y); o.z = f2bf(v.z); o.w = f2bf(v.w);
        *(ushort4*)&xb[i] = o;
    } else if (b < 8192) {
        int i = ((b - 4096) * 256 + threadIdx.x) * 4;   // over 4 x 1M
        int sel = i >> 20;
        int off = i & ((1 << 20) - 1);
        const float* src = (sel == 0) ? Wq : (sel == 1) ? Wk : (sel == 2) ? Wv : Wo;
        float4 v = *(const float4*)&src[off];
        ushort4 o;
        o.x = f2bf(v.x); o.y = f2bf(v.y); o.z = f2bf(v.z); o.w = f2bf(v.w);
        *(ushort4*)&Wb[i] = o;
    } else {
        // extended table [4096][64]: k<32 real RoPE, k>=32 identity (for V cols)
        int i = (b - 8192) * 256 + threadIdx.x;   // [0, 4096*64)
        int s = i >> 6, k = i & 63;
        if (k < 32) {
            float invf = __builtin_exp2f(-(float)(2 * k) * (1.0f / 64.0f) * 13.287712379549449f);
            float ang = (float)pos[s] * invf;
            ct[i] = cosf(ang);
            st[i] = sinf(ang);
        } else {
            ct[i] = 1.0f;
            st[i] = 0.0f;
        }
    }
}

// ---------------- V transpose: QKV V-cols [S][3072 (+2048)] -> Vt [1024][S] ----------------
__global__ __launch_bounds__(256) void vtrans_k(const unsigned short* __restrict__ src,
                                                unsigned short* __restrict__ dst) {
    __shared__ unsigned short tile[64 * 68];
    const int bs = blockIdx.x * 64;   // s tile
    const int bd = blockIdx.y * 64;   // d tile
    const int t = threadIdx.x;
    {
        int col = (t & 7) * 8;
        #pragma unroll
        for (int rr = 0; rr < 2; ++rr) {
            int row = rr * 32 + (t >> 3);
            const unsigned short* g = src + (size_t)(bs + row) * LDQKV + bd + col;
            ushort4 a = *(const ushort4*)g;
            ushort4 b = *(const ushort4*)(g + 4);
            *(ushort4*)&tile[row * 68 + col] = a;
            *(ushort4*)&tile[row * 68 + col + 4] = b;
        }
    }
    __syncthreads();
    {
        int dl = t >> 2;             // 0..63 d row
        int sc = (t & 3) * 16;       // s chunk
        ushort4 o[4];
        #pragma unroll
        for (int e = 0; e < 16; ++e)
            ((unsigned short*)o)[e] = tile[(sc + e) * 68 + dl];
        unsigned short* g = dst + (size_t)(bd + dl) * S_LEN + bs + sc;
        *(ushort4*)(g + 0)  = o[0];
        *(ushort4*)(g + 4)  = o[1];
        *(ushort4*)(g + 8)  = o[2];
        *(ushort4*)(g + 12) = o[3];
    }
}

// ---------------- fused QKV GEMM: C[S][3072] = x * [Wq;Wk;Wv]^T ----------------
// 128x128 tiles, grid (24,32) = 768 blocks = 3/CU. Branchless epilogue:
// RoPE via extended table (identity rows for V cols), single store site.
__global__ __launch_bounds__(256) void gemm_qkv_k(const unsigned short* __restrict__ A,
                                                  const unsigned short* __restrict__ B,
                                                  unsigned short* __restrict__ C,
                                                  const float* __restrict__ ct,
                                                  const float* __restrict__ st) {
    __shared__ unsigned short lA[128 * 64];
    __shared__ unsigned short lB[128 * 64];
    const int t = threadIdx.x, w = t >> 6, l = t & 63;
    const int tm = blockIdx.y * 128, tn = blockIdx.x * 128;
    const int wm = (w >> 1) * 64, wn = (w & 1) * 64;
    const int g = l >> 4, ln = l & 15;

    f32x4 acc[4][4] = {};

    for (int k0 = 0; k0 < 1024; k0 += 64) {
        #pragma unroll
        for (int r = 0; r < 4; ++r) {
            int row = 8 * (4 * r + w) + (l >> 3);
            gld_lds16(A + (size_t)(tm + row) * 1024 + k0 + (l & 7) * 8, &lA[(4 * r + w) * 512]);
            gld_lds16(B + (size_t)(tn + row) * 1024 + k0 + (l & 7) * 8, &lB[(4 * r + w) * 512]);
        }
        asm volatile("s_waitcnt vmcnt(0)" ::: "memory");
        __syncthreads();

        #pragma unroll
        for (int kk = 0; kk < 2; ++kk) {
            bf16x8 af[4], bf[4];
            #pragma unroll
            for (int i = 0; i < 4; ++i) {
                af[i] = *(const bf16x8*)&lA[(wm + i * 16 + ln) * 64 + kk * 32 + g * 8];
                bf[i] = *(const bf16x8*)&lB[(wn + i * 16 + ln) * 64 + kk * 32 + g * 8];
            }
            #pragma unroll
            for (int i = 0; i < 4; ++i)
                #pragma unroll
                for (int j = 0; j < 4; ++j)
                    acc[i][j] = __builtin_amdgcn_mfma_f32_16x16x32_bf16(af[i], bf[j], acc[i][j], 0, 0, 0);
        }
        __syncthreads();
    }

    // epilogue: RoPE (identity for V) + Q pre-scale, all lanes same path
    #pragma unroll
    for (int i = 0; i < 4; ++i) {
        #pragma unroll
        for (int j = 0; j < 4; ++j) {
            int col = tn + wn + j * 16 + ln;
            int dd = col & 63;
            int tb = ((col >= 2048) ? 32 : 0) + (dd >> 1);
            float scl = (col < 1024) ? SCALE_LOG2E : 1.0f;
            #pragma unroll
            for (int r = 0; r < 4; ++r) {
                int row = tm + wm + i * 16 + g * 4 + r;
                float v = acc[i][j][r];
                float p = __shfl_xor(v, 1, 64);
                float c = ct[row * 64 + tb];
                float s = st[row * 64 + tb];
                v = ((dd & 1) ? (s * p + c * v) : (c * v - s * p)) * scl;
                C[(size_t)row * LDQKV + col] = f2bf(v);
            }
        }
    }
}

// ---------------- out GEMM: out[S][1024] f32 = ctx * Wo^T, 64x128 tiles ----------------
// grid (8,64) = 512 blocks = 2/CU (vs 1/CU at 128x128) for latency hiding.
__global__ __launch_bounds__(256) void gemm_o_k(const unsigned short* __restrict__ A,
                                                const unsigned short* __restrict__ B,
                                                float* __restrict__ C) {
    __shared__ unsigned short lA[64 * 64];    // 8 KB
    __shared__ unsigned short lB[128 * 64];   // 16 KB
    const int t = threadIdx.x, w = t >> 6, l = t & 63;
    const int tm = blockIdx.y * 64, tn = blockIdx.x * 128;
    const int wm = (w >> 1) * 32, wn = (w & 1) * 64;
    const int g = l >> 4, ln = l & 15;

    f32x4 acc[2][4] = {};

    for (int k0 = 0; k0 < 1024; k0 += 64) {
        #pragma unroll
        for (int r = 0; r < 2; ++r) {
            int row = r * 32 + w * 8 + (l >> 3);
            gld_lds16(A + (size_t)(tm + row) * 1024 + k0 + (l & 7) * 8, &lA[(r * 32 + w * 8) * 64]);
        }
        #pragma unroll
        for (int r = 0; r < 4; ++r) {
            int row = 8 * (4 * r + w) + (l >> 3);
            gld_lds16(B + (size_t)(tn + row) * 1024 + k0 + (l & 7) * 8, &lB[(4 * r + w) * 512]);
        }
        asm volatile("s_waitcnt vmcnt(0)" ::: "memory");
        __syncthreads();

        #pragma unroll
        for (int kk = 0; kk < 2; ++kk) {
            bf16x8 af[2], bf[4];
            #pragma unroll
            for (int i = 0; i < 2; ++i)
                af[i] = *(const bf16x8*)&lA[(wm + i * 16 + ln) * 64 + kk * 32 + g * 8];
            #pragma unroll
            for (int j = 0; j < 4; ++j)
                bf[j] = *(const bf16x8*)&lB[(wn + j * 16 + ln) * 64 + kk * 32 + g * 8];
            #pragma unroll
            for (int i = 0; i < 2; ++i)
                #pragma unroll
                for (int j = 0; j < 4; ++j)
                    acc[i][j] = __builtin_amdgcn_mfma_f32_16x16x32_bf16(af[i], bf[j], acc[i][j], 0, 0, 0);
        }
        __syncthreads();
    }

    #pragma unroll
    for (int i = 0; i < 2; ++i)
        #pragma unroll
        for (int j = 0; j < 4; ++j) {
            int col = tn + wn + j * 16 + ln;
            #pragma unroll
            for (int r = 0; r < 4; ++r) {
                int row = tm + wm + i * 16 + g * 4 + r;
                C[(size_t)row * 1024 + col] = acc[i][j][r];
            }
        }
}

// ---------------- causal flash attention, PAIRED q-tiles (R10 structure) ----------
__device__ __forceinline__ void stage8(const unsigned short* __restrict__ Kb,
                                       const unsigned short* __restrict__ Vt,
                                       unsigned short* lK, unsigned short* lV,
                                       int h, int kt, int w, int l) {
    const int half = w & 3;
    const int chunk = (l & 7) ^ (l >> 3);   // source pre-swizzle (row&7 == l>>3)
    if (w < 4) {
        #pragma unroll
        for (int r2 = 0; r2 < 2; ++r2) {
            int row = half * 16 + r2 * 8 + (l >> 3);
            gld_lds16(Kb + (size_t)(kt * 64 + row) * LDQKV + h * 64 + chunk * 8,
                      lK + half * 1024 + r2 * 512);
        }
    } else {
        #pragma unroll
        for (int r2 = 0; r2 < 2; ++r2) {
            int row = half * 16 + r2 * 8 + (l >> 3);
            gld_lds16(Vt + (size_t)(h * 64 + row) * S_LEN + kt * 64 + chunk * 8,
                      lV + half * 1024 + r2 * 512);
        }
    }
}

__global__ __launch_bounds__(512) void attn_k(const unsigned short* __restrict__ Qb,
                                              const unsigned short* __restrict__ Kb,
                                              const unsigned short* __restrict__ Vt,
                                              unsigned short* __restrict__ ctxb) {
    __shared__ unsigned short lK[2][64 * 64];
    __shared__ unsigned short lV[2][64 * 64];
    __shared__ unsigned short lP[8][16 * 64];

    const int t = threadIdx.x, w = t >> 6, l = t & 63;
    const int wv = w & 3;
    const int sel = w >> 2;
    const int h = blockIdx.x;
    const int qA = blockIdx.y;              // 0..31
    const int qB = 63 - qA;                 // 32..63
    const int qT = sel ? qB : qA;
    const int q0 = qT * 64 + wv * 16;
    const int g = l >> 4, ln = l & 15;

    bf16x8 aq[2];
    #pragma unroll
    for (int kk = 0; kk < 2; ++kk)
        aq[kk] = *(const bf16x8*)&Qb[(size_t)(q0 + ln) * LDQKV + h * 64 + kk * 32 + g * 8];

    f32x4 acc[4] = {};
    float rm = -INFINITY, rs = 0.0f;
    char* lpw = (char*)&lP[w][0];

    stage8(Kb, Vt, &lK[0][0], &lV[0][0], h, 0, w, l);
    asm volatile("s_waitcnt vmcnt(0)" ::: "memory");
    __syncthreads();

    int cur = 0;
    for (int kt = 0; kt <= qB; ++kt) {
        if (kt < qB)
            stage8(Kb, Vt, &lK[cur ^ 1][0], &lV[cur ^ 1][0], h, kt + 1, w, l);

        if (kt <= qT) {
            float p[16];
            __builtin_amdgcn_s_setprio(1);
            #pragma unroll
            for (int ct = 0; ct < 4; ++ct) {
                f32x4 z = {};
                #pragma unroll
                for (int kk = 0; kk < 2; ++kk) {
                    int row = ct * 16 + ln;
                    int off = (row * 128 + kk * 64 + g * 16) ^ ((row & 7) << 4);
                    bf16x8 ak = *(const bf16x8*)((const char*)&lK[cur][0] + off);
                    z = __builtin_amdgcn_mfma_f32_16x16x32_bf16(ak, aq[kk], z, 0, 0, 0);
                }
                #pragma unroll
                for (int r = 0; r < 4; ++r) p[ct * 4 + r] = z[r];
            }
            __builtin_amdgcn_s_setprio(0);

            if (kt == qT) {
                int qg = q0 + ln;
                #pragma unroll
                for (int ct = 0; ct < 4; ++ct)
                    #pragma unroll
                    for (int r = 0; r < 4; ++r)
                        if (kt * 64 + ct * 16 + g * 4 + r > qg) p[ct * 4 + r] = -INFINITY;
            }

            float pmax = fmaxf(p[0], p[1]);
            #pragma unroll
            for (int i = 2; i < 16; i += 2)
                pmax = fmaxf(fmaxf(pmax, p[i]), p[i + 1]);
            pmax = fmaxf(pmax, __shfl_xor(pmax, 16, 64));
            pmax = fmaxf(pmax, __shfl_xor(pmax, 32, 64));
            if (__any(pmax > rm + 8.0f)) {
                float mn = fmaxf(rm, pmax);
                float fac = __builtin_amdgcn_exp2f(rm - mn);
                rm = mn;
                rs *= fac;
                #pragma unroll
                for (int mb = 0; mb < 4; ++mb) {
                    f32x4 a = acc[mb];
                    #pragma unroll
                    for (int r = 0; r < 4; ++r) a[r] *= fac;
                    acc[mb] = a;
                }
            }
            float ps = 0.0f;
            #pragma unroll
            for (int i = 0; i < 16; ++i) {
                float e = __builtin_amdgcn_exp2f(p[i] - rm);
                p[i] = e;
                ps += e;
            }
            ps += __shfl_xor(ps, 16, 64);
            ps += __shfl_xor(ps, 32, 64);
            rs += ps;

            #pragma unroll
            for (int ct = 0; ct < 4; ++ct) {
                bf16x4 pv;
                pv[0] = (__bf16)p[ct * 4 + 0];
                pv[1] = (__bf16)p[ct * 4 + 1];
                pv[2] = (__bf16)p[ct * 4 + 2];
                pv[3] = (__bf16)p[ct * 4 + 3];
                int off = (ln * 128 + ct * 32 + g * 8) ^ ((ln & 7) << 4);
                *(bf16x4*)(lpw + off) = pv;
            }

            __builtin_amdgcn_s_setprio(1);
            #pragma unroll
            for (int mb = 0; mb < 4; ++mb) {
                #pragma unroll
                for (int kc = 0; kc < 2; ++kc) {
                    int vrow = mb * 16 + ln;
                    int voff = (vrow * 128 + kc * 64 + g * 16) ^ ((vrow & 7) << 4);
                    bf16x8 av = *(const bf16x8*)((const char*)&lV[cur][0] + voff);
                    int poff = (ln * 128 + kc * 64 + g * 16) ^ ((ln & 7) << 4);
                    bf16x8 bp = *(const bf16x8*)(lpw + poff);
                    acc[mb] = __builtin_amdgcn_mfma_f32_16x16x32_bf16(av, bp, acc[mb], 0, 0, 0);
                }
            }
            __builtin_amdgcn_s_setprio(0);
        }

        asm volatile("s_waitcnt vmcnt(0)" ::: "memory");
        __syncthreads();
        cur ^= 1;
    }

    float inv = 1.0f / rs;
    #pragma unroll
    for (int mb = 0; mb < 4; ++mb) {
        bf16x4 o;
        #pragma unroll
        for (int r = 0; r < 4; ++r) o[r] = (__bf16)(acc[mb][r] * inv);
        *(bf16x4*)&ctxb[(size_t)(q0 + ln) * D_MODEL + h * 64 + mb * 16 + g * 4] = o;
    }
}

// ---------------- host side ----------------
extern "C" void kernel_launch(void* const* d_in, const int* in_sizes, int n_in,
                              void* d_out, int out_size, void* d_ws, size_t ws_size,
                              hipStream_t stream) {
    const float* x  = (const float*)d_in[0];
    const float* Wq = (const float*)d_in[1];
    const float* Wk = (const float*)d_in[2];
    const float* Wv = (const float*)d_in[3];
    const float* Wo = (const float*)d_in[4];
    const int* tpos = (const int*)d_in[5];
    float* out = (float*)d_out;

    char* ws = (char*)d_ws;
    unsigned short* xb   = (unsigned short*)(ws + 0);            // 8 MB (dead after QKV gemm)
    unsigned short* Wb   = (unsigned short*)(ws + (8u << 20));   // 8 MB (Wq,Wk,Wv,Wo bf16)
    unsigned short* QKV  = (unsigned short*)(ws + (16u << 20));  // 24 MB [S][3072]
    unsigned short* ctxb = (unsigned short*)(ws + (40u << 20));  // 8 MB
    float* costab = (float*)(ws + (48u << 20));                  // 1 MB [4096][64]
    float* sintab = (float*)(ws + (49u << 20));                  // 1 MB
    unsigned short* Vtb  = xb;   // reuse: written by vtrans after QKV gemm

    // prep: x->bf16 | weights->bf16 | extended RoPE tables
    prep_k<<<9216, 256, 0, stream>>>(x, Wq, Wk, Wv, Wo, tpos, xb, Wb, costab, sintab);

    // fused QKV projection with RoPE/scale epilogue: 768 blocks = 3/CU
    gemm_qkv_k<<<dim3(24, 32), 256, 0, stream>>>(xb, Wb, QKV, costab, sintab);

    // V transpose: QKV cols 2048.. -> Vt [1024][S]
    vtrans_k<<<dim3(S_LEN / 64, D_MODEL / 64), 256, 0, stream>>>(QKV + 2048, Vtb);

    // paired causal attention: 32 balanced blocks per head
    attn_k<<<dim3(N_HEADS, 32), 512, 0, stream>>>(QKV, QKV + 1024, Vtb, ctxb);

    // out projection, 64x128 tiles: 512 blocks = 2/CU
    gemm_o_k<<<dim3(8, 64), 256, 0, stream>>>(ctxb, Wb + 3u * 1024 * 1024, out);
}

// Round 12
// 164.902 us; speedup vs baseline: 2.4929x; 1.0026x over previous
//
#include <hip/hip_runtime.h>
#include <hip/hip_bf16.h>
#include <stdint.h>

#define S_LEN 4096
#define D_MODEL 1024
#define N_HEADS 16
#define D_HEAD 64
#define LDQKV 3072
#define SCALE_LOG2E 0.1803368787f   // (1/sqrt(64)) * log2(e)

typedef __attribute__((ext_vector_type(4))) float f32x4;
typedef __attribute__((ext_vector_type(8))) __bf16 bf16x8;
typedef __attribute__((ext_vector_type(4))) __bf16 bf16x4;

__device__ __forceinline__ unsigned short f2bf(float f) {
    union { float f; unsigned u; } x{f};
    unsigned r = x.u + 0x7fff + ((x.u >> 16) & 1);
    return (unsigned short)(r >> 16);
}

__device__ __forceinline__ void gld_lds16(const void* g, void* l) {
    __builtin_amdgcn_global_load_lds(
        (const __attribute__((address_space(1))) unsigned int*)g,
        (__attribute__((address_space(3))) unsigned int*)l, 16, 0, 0);
}

// ---------------- fused prep: x->bf16, weights->bf16, RoPE tables ----------------
__global__ __launch_bounds__(256) void prep_k(const float* __restrict__ x,
                                              const float* __restrict__ Wq,
                                              const float* __restrict__ Wk,
                                              const float* __restrict__ Wv,
                                              const float* __restrict__ Wo,
                                              const int* __restrict__ pos,
                                              unsigned short* __restrict__ xb,
                                              unsigned short* __restrict__ Wb,
                                              float* __restrict__ ct,
                                              float* __restrict__ st) {
    int b = blockIdx.x;
    if (b < 4096) {
        int i = (b * 256 + threadIdx.x) * 4;
        float4 v = *(const float4*)&x[i];
        ushort4 o;
        o.x = f2bf(v.x); o.y = f2bf(v.y); o.z = f2bf(v.z); o.w = f2bf(v.w);
        *(ushort4*)&xb[i] = o;
    } else if (b < 8192) {
        int i = ((b - 4096) * 256 + threadIdx.x) * 4;   // over 4 x 1M
        int sel = i >> 20;
        int off = i & ((1 << 20) - 1);
        const float* src = (sel == 0) ? Wq : (sel == 1) ? Wk : (sel == 2) ? Wv : Wo;
        float4 v = *(const float4*)&src[off];
        ushort4 o;
        o.x = f2bf(v.x); o.y = f2bf(v.y); o.z = f2bf(v.z); o.w = f2bf(v.w);
        *(ushort4*)&Wb[i] = o;
    } else {
        // extended table [4096][64]: k<32 real RoPE, k>=32 identity (for V cols)
        int i = (b - 8192) * 256 + threadIdx.x;   // [0, 4096*64)
        int s = i >> 6, k = i & 63;
        if (k < 32) {
            float invf = __builtin_exp2f(-(float)(2 * k) * (1.0f / 64.0f) * 13.287712379549449f);
            float ang = (float)pos[s] * invf;
            ct[i] = cosf(ang);
            st[i] = sinf(ang);
        } else {
            ct[i] = 1.0f;
            st[i] = 0.0f;
        }
    }
}

// ---------------- V transpose: QKV V-cols [S][3072 (+2048)] -> Vt [1024][S] ----------------
__global__ __launch_bounds__(256) void vtrans_k(const unsigned short* __restrict__ src,
                                                unsigned short* __restrict__ dst) {
    __shared__ unsigned short tile[64 * 68];
    const int bs = blockIdx.x * 64;   // s tile
    const int bd = blockIdx.y * 64;   // d tile
    const int t = threadIdx.x;
    {
        int col = (t & 7) * 8;
        #pragma unroll
        for (int rr = 0; rr < 2; ++rr) {
            int row = rr * 32 + (t >> 3);
            const unsigned short* g = src + (size_t)(bs + row) * LDQKV + bd + col;
            ushort4 a = *(const ushort4*)g;
            ushort4 b = *(const ushort4*)(g + 4);
            *(ushort4*)&tile[row * 68 + col] = a;
            *(ushort4*)&tile[row * 68 + col + 4] = b;
        }
    }
    __syncthreads();
    {
        int dl = t >> 2;             // 0..63 d row
        int sc = (t & 3) * 16;       // s chunk
        ushort4 o[4];
        #pragma unroll
        for (int e = 0; e < 16; ++e)
            ((unsigned short*)o)[e] = tile[(sc + e) * 68 + dl];
        unsigned short* g = dst + (size_t)(bd + dl) * S_LEN + bs + sc;
        *(ushort4*)(g + 0)  = o[0];
        *(ushort4*)(g + 4)  = o[1];
        *(ushort4*)(g + 8)  = o[2];
        *(ushort4*)(g + 12) = o[3];
    }
}

// ---------------- fused QKV GEMM: C[S][3072] = x * [Wq;Wk;Wv]^T ----------------
__global__ __launch_bounds__(256) void gemm_qkv_k(const unsigned short* __restrict__ A,
                                                  const unsigned short* __restrict__ B,
                                                  unsigned short* __restrict__ C,
                                                  const float* __restrict__ ct,
                                                  const float* __restrict__ st) {
    __shared__ unsigned short lA[128 * 64];
    __shared__ unsigned short lB[128 * 64];
    const int t = threadIdx.x, w = t >> 6, l = t & 63;
    const int tm = blockIdx.y * 128, tn = blockIdx.x * 128;
    const int wm = (w >> 1) * 64, wn = (w & 1) * 64;
    const int g = l >> 4, ln = l & 15;

    f32x4 acc[4][4] = {};

    for (int k0 = 0; k0 < 1024; k0 += 64) {
        #pragma unroll
        for (int r = 0; r < 4; ++r) {
            int row = 8 * (4 * r + w) + (l >> 3);
            gld_lds16(A + (size_t)(tm + row) * 1024 + k0 + (l & 7) * 8, &lA[(4 * r + w) * 512]);
            gld_lds16(B + (size_t)(tn + row) * 1024 + k0 + (l & 7) * 8, &lB[(4 * r + w) * 512]);
        }
        asm volatile("s_waitcnt vmcnt(0)" ::: "memory");
        __syncthreads();

        #pragma unroll
        for (int kk = 0; kk < 2; ++kk) {
            bf16x8 af[4], bf[4];
            #pragma unroll
            for (int i = 0; i < 4; ++i) {
                af[i] = *(const bf16x8*)&lA[(wm + i * 16 + ln) * 64 + kk * 32 + g * 8];
                bf[i] = *(const bf16x8*)&lB[(wn + i * 16 + ln) * 64 + kk * 32 + g * 8];
            }
            #pragma unroll
            for (int i = 0; i < 4; ++i)
                #pragma unroll
                for (int j = 0; j < 4; ++j)
                    acc[i][j] = __builtin_amdgcn_mfma_f32_16x16x32_bf16(af[i], bf[j], acc[i][j], 0, 0, 0);
        }
        __syncthreads();
    }

    // epilogue: RoPE (identity for V) + Q pre-scale, all lanes same path
    #pragma unroll
    for (int i = 0; i < 4; ++i) {
        #pragma unroll
        for (int j = 0; j < 4; ++j) {
            int col = tn + wn + j * 16 + ln;
            int dd = col & 63;
            int tb = ((col >= 2048) ? 32 : 0) + (dd >> 1);
            float scl = (col < 1024) ? SCALE_LOG2E : 1.0f;
            #pragma unroll
            for (int r = 0; r < 4; ++r) {
                int row = tm + wm + i * 16 + g * 4 + r;
                float v = acc[i][j][r];
                float p = __shfl_xor(v, 1, 64);
                float c = ct[row * 64 + tb];
                float s = st[row * 64 + tb];
                v = ((dd & 1) ? (s * p + c * v) : (c * v - s * p)) * scl;
                C[(size_t)row * LDQKV + col] = f2bf(v);
            }
        }
    }
}

// ---------------- out GEMM: out[S][1024] f32 = ctx * Wo^T, 64x128 tiles ----------------
__global__ __launch_bounds__(256) void gemm_o_k(const unsigned short* __restrict__ A,
                                                const unsigned short* __restrict__ B,
                                                float* __restrict__ C) {
    __shared__ unsigned short lA[64 * 64];    // 8 KB
    __shared__ unsigned short lB[128 * 64];   // 16 KB
    const int t = threadIdx.x, w = t >> 6, l = t & 63;
    const int tm = blockIdx.y * 64, tn = blockIdx.x * 128;
    const int wm = (w >> 1) * 32, wn = (w & 1) * 64;
    const int g = l >> 4, ln = l & 15;

    f32x4 acc[2][4] = {};

    for (int k0 = 0; k0 < 1024; k0 += 64) {
        #pragma unroll
        for (int r = 0; r < 2; ++r) {
            int row = r * 32 + w * 8 + (l >> 3);
            gld_lds16(A + (size_t)(tm + row) * 1024 + k0 + (l & 7) * 8, &lA[(r * 32 + w * 8) * 64]);
        }
        #pragma unroll
        for (int r = 0; r < 4; ++r) {
            int row = 8 * (4 * r + w) + (l >> 3);
            gld_lds16(B + (size_t)(tn + row) * 1024 + k0 + (l & 7) * 8, &lB[(4 * r + w) * 512]);
        }
        asm volatile("s_waitcnt vmcnt(0)" ::: "memory");
        __syncthreads();

        #pragma unroll
        for (int kk = 0; kk < 2; ++kk) {
            bf16x8 af[2], bf[4];
            #pragma unroll
            for (int i = 0; i < 2; ++i)
                af[i] = *(const bf16x8*)&lA[(wm + i * 16 + ln) * 64 + kk * 32 + g * 8];
            #pragma unroll
            for (int j = 0; j < 4; ++j)
                bf[j] = *(const bf16x8*)&lB[(wn + j * 16 + ln) * 64 + kk * 32 + g * 8];
            #pragma unroll
            for (int i = 0; i < 2; ++i)
                #pragma unroll
                for (int j = 0; j < 4; ++j)
                    acc[i][j] = __builtin_amdgcn_mfma_f32_16x16x32_bf16(af[i], bf[j], acc[i][j], 0, 0, 0);
        }
        __syncthreads();
    }

    #pragma unroll
    for (int i = 0; i < 2; ++i)
        #pragma unroll
        for (int j = 0; j < 4; ++j) {
            int col = tn + wn + j * 16 + ln;
            #pragma unroll
            for (int r = 0; r < 4; ++r) {
                int row = tm + wm + i * 16 + g * 4 + r;
                C[(size_t)row * 1024 + col] = acc[i][j][r];
            }
        }
}

// ---------------- causal flash attention: paired q-tiles + phase-2 kv-split ----
// Phase 1 (kt<=qA): waves 0-3 on qA, 4-7 on qB, full k (two half-calls).
// Phase 2 (kt>qA): all 8 waves on qB; pair (w, w+4) splits each tile's k in
// half (kc=sel). Light waves flush qA output at kt==qA and restart a fresh
// state; partner states merge through LDS at the end. Per-block wave work is
// exactly uniform (520 half-tile units).
__device__ __forceinline__ void stage8(const unsigned short* __restrict__ Kb,
                                       const unsigned short* __restrict__ Vt,
                                       unsigned short* lK, unsigned short* lV,
                                       int h, int kt, int w, int l) {
    const int half = w & 3;
    const int chunk = (l & 7) ^ (l >> 3);   // source pre-swizzle (row&7 == l>>3)
    if (w < 4) {
        #pragma unroll
        for (int r2 = 0; r2 < 2; ++r2) {
            int row = half * 16 + r2 * 8 + (l >> 3);
            gld_lds16(Kb + (size_t)(kt * 64 + row) * LDQKV + h * 64 + chunk * 8,
                      lK + half * 1024 + r2 * 512);
        }
    } else {
        #pragma unroll
        for (int r2 = 0; r2 < 2; ++r2) {
            int row = half * 16 + r2 * 8 + (l >> 3);
            gld_lds16(Vt + (size_t)(h * 64 + row) * S_LEN + kt * 64 + chunk * 8,
                      lV + half * 1024 + r2 * 512);
        }
    }
}

// one k-half of one kv-tile: QK^T (ct=2kc,2kc+1) -> online softmax -> PV (kc)
__device__ __forceinline__ void do_half(const char* lKc, const char* lVc, char* lpw,
                                        const bf16x8* aq, f32x4* acc,
                                        float& rm, float& rs,
                                        int kc, bool diag, int kbase, int qg,
                                        int g, int ln) {
    float p[8];
    __builtin_amdgcn_s_setprio(1);
    #pragma unroll
    for (int c2 = 0; c2 < 2; ++c2) {
        int ct = 2 * kc + c2;
        f32x4 z = {};
        #pragma unroll
        for (int kk = 0; kk < 2; ++kk) {
            int row = ct * 16 + ln;
            int off = (row * 128 + kk * 64 + g * 16) ^ ((row & 7) << 4);
            bf16x8 ak = *(const bf16x8*)(lKc + off);
            z = __builtin_amdgcn_mfma_f32_16x16x32_bf16(ak, aq[kk], z, 0, 0, 0);
        }
        #pragma unroll
        for (int r = 0; r < 4; ++r) p[c2 * 4 + r] = z[r];
    }
    __builtin_amdgcn_s_setprio(0);

    if (diag) {
        #pragma unroll
        for (int c2 = 0; c2 < 2; ++c2)
            #pragma unroll
            for (int r = 0; r < 4; ++r)
                if (kbase + (2 * kc + c2) * 16 + g * 4 + r > qg) p[c2 * 4 + r] = -INFINITY;
    }

    float pmax = fmaxf(p[0], p[1]);
    #pragma unroll
    for (int i = 2; i < 8; i += 2)
        pmax = fmaxf(fmaxf(pmax, p[i]), p[i + 1]);
    pmax = fmaxf(pmax, __shfl_xor(pmax, 16, 64));
    pmax = fmaxf(pmax, __shfl_xor(pmax, 32, 64));
    if (__any(pmax > rm + 8.0f)) {
        float mn = fmaxf(rm, pmax);
        float fac = __builtin_amdgcn_exp2f(rm - mn);
        rm = mn;
        rs *= fac;
        #pragma unroll
        for (int mb = 0; mb < 4; ++mb) {
            f32x4 a = acc[mb];
            #pragma unroll
            for (int r = 0; r < 4; ++r) a[r] *= fac;
            acc[mb] = a;
        }
    }
    float ps = 0.0f;
    #pragma unroll
    for (int i = 0; i < 8; ++i) {
        float e = __builtin_amdgcn_exp2f(p[i] - rm);
        p[i] = e;
        ps += e;
    }
    ps += __shfl_xor(ps, 16, 64);
    ps += __shfl_xor(ps, 32, 64);
    rs += ps;

    // pack 8 P values (bf16) to wave-private LDS (compiler-ordered RAW)
    #pragma unroll
    for (int c2 = 0; c2 < 2; ++c2) {
        bf16x4 pv;
        pv[0] = (__bf16)p[c2 * 4 + 0];
        pv[1] = (__bf16)p[c2 * 4 + 1];
        pv[2] = (__bf16)p[c2 * 4 + 2];
        pv[3] = (__bf16)p[c2 * 4 + 3];
        int off = (ln * 128 + (2 * kc + c2) * 32 + g * 8) ^ ((ln & 7) << 4);
        *(bf16x4*)(lpw + off) = pv;
    }

    int poff = (ln * 128 + kc * 64 + g * 16) ^ ((ln & 7) << 4);
    bf16x8 bp = *(const bf16x8*)(lpw + poff);
    __builtin_amdgcn_s_setprio(1);
    #pragma unroll
    for (int mb = 0; mb < 4; ++mb) {
        int vrow = mb * 16 + ln;
        int voff = (vrow * 128 + kc * 64 + g * 16) ^ ((vrow & 7) << 4);
        bf16x8 av = *(const bf16x8*)(lVc + voff);
        acc[mb] = __builtin_amdgcn_mfma_f32_16x16x32_bf16(av, bp, acc[mb], 0, 0, 0);
    }
    __builtin_amdgcn_s_setprio(0);
}

__global__ __launch_bounds__(512) void attn_k(const unsigned short* __restrict__ Qb,
                                              const unsigned short* __restrict__ Kb,
                                              const unsigned short* __restrict__ Vt,
                                              unsigned short* __restrict__ ctxb) {
    __shared__ unsigned short lK[2][64 * 64];   // 16 KB (reused for merge)
    __shared__ unsigned short lV[2][64 * 64];   // 16 KB
    __shared__ unsigned short lP[8][16 * 64];   // 16 KB (rm/rs merge area too)

    const int t = threadIdx.x, w = t >> 6, l = t & 63;
    const int wv = w & 3;
    const int sel = w >> 2;                 // 0: light (qA) then k-lo of qB; 1: qB k-hi
    const int h = blockIdx.x;
    const int qA = blockIdx.y;              // 0..31
    const int qB = 63 - qA;                 // 32..63
    const int qOwn = sel ? qB : qA;
    const int q0own = qOwn * 64 + wv * 16;
    const int q0B = qB * 64 + wv * 16;
    const int g = l >> 4, ln = l & 15;

    bf16x8 aqOwn[2], aqB[2];
    #pragma unroll
    for (int kk = 0; kk < 2; ++kk) {
        aqOwn[kk] = *(const bf16x8*)&Qb[(size_t)(q0own + ln) * LDQKV + h * 64 + kk * 32 + g * 8];
        aqB[kk]   = *(const bf16x8*)&Qb[(size_t)(q0B + ln) * LDQKV + h * 64 + kk * 32 + g * 8];
    }

    f32x4 acc[4] = {};
    float rm = -INFINITY, rs = 0.0f;
    char* lpw = (char*)&lP[w][0];

    stage8(Kb, Vt, &lK[0][0], &lV[0][0], h, 0, w, l);
    asm volatile("s_waitcnt vmcnt(0)" ::: "memory");
    __syncthreads();

    int cur = 0;
    for (int kt = 0; kt <= qB; ++kt) {
        if (kt < qB)
            stage8(Kb, Vt, &lK[cur ^ 1][0], &lV[cur ^ 1][0], h, kt + 1, w, l);

        const char* lKc = (const char*)&lK[cur][0];
        const char* lVc = (const char*)&lV[cur][0];

        if (kt <= qA) {
            // phase 1: full tile on own q-tile (two half-calls)
            bool diag = (kt == qOwn);
            do_half(lKc, lVc, lpw, aqOwn, acc, rm, rs, 0, diag, kt * 64, q0own + ln, g, ln);
            do_half(lKc, lVc, lpw, aqOwn, acc, rm, rs, 1, diag, kt * 64, q0own + ln, g, ln);
            if (sel == 0 && kt == qA) {
                // light tile complete: flush ctx, reset state for phase-2 partial
                float inv = 1.0f / rs;
                #pragma unroll
                for (int mb = 0; mb < 4; ++mb) {
                    bf16x4 o;
                    #pragma unroll
                    for (int r = 0; r < 4; ++r) o[r] = (__bf16)(acc[mb][r] * inv);
                    *(bf16x4*)&ctxb[(size_t)(q0own + ln) * D_MODEL + h * 64 + mb * 16 + g * 4] = o;
                }
                rm = -INFINITY;
                rs = 0.0f;
                #pragma unroll
                for (int mb = 0; mb < 4; ++mb) acc[mb] = f32x4{};
            }
        } else {
            // phase 2: all waves on qB, k-half = sel
            bool diag = (kt == qB);
            do_half(lKc, lVc, lpw, aqB, acc, rm, rs, sel, diag, kt * 64, q0B + ln, g, ln);
        }

        asm volatile("s_waitcnt vmcnt(0)" ::: "memory");
        __syncthreads();
        cur ^= 1;
    }

    // ---- merge partner states (w <-> w+4) for qB rows ----
    float* lKf = (float*)&lK[0][0];          // 4 waves x 64 lanes x 16 f32 = 16 KB
    float* lPf = (float*)&lP[0][0];          // rm/rs: 4 x 64 x 2 f32
    if (sel == 0) {
        #pragma unroll
        for (int mb = 0; mb < 4; ++mb)
            *(f32x4*)&lKf[(size_t)(w * 64 + l) * 16 + mb * 4] = acc[mb];
        lPf[(w * 64 + l) * 2 + 0] = rm;
        lPf[(w * 64 + l) * 2 + 1] = rs;
    }
    __syncthreads();
    if (sel == 1) {
        int pw = w - 4;
        float rm2 = lPf[(pw * 64 + l) * 2 + 0];
        float rs2 = lPf[(pw * 64 + l) * 2 + 1];
        float m = fmaxf(rm, rm2);
        float f1 = __builtin_amdgcn_exp2f(rm - m);
        float f2 = __builtin_amdgcn_exp2f(rm2 - m);
        float inv = 1.0f / (rs * f1 + rs2 * f2);
        #pragma unroll
        for (int mb = 0; mb < 4; ++mb) {
            f32x4 a2 = *(const f32x4*)&lKf[(size_t)(pw * 64 + l) * 16 + mb * 4];
            bf16x4 o;
            #pragma unroll
            for (int r = 0; r < 4; ++r)
                o[r] = (__bf16)((acc[mb][r] * f1 + a2[r] * f2) * inv);
            *(bf16x4*)&ctxb[(size_t)(q0B + ln) * D_MODEL + h * 64 + mb * 16 + g * 4] = o;
        }
    }
}

// ---------------- host side ----------------
extern "C" void kernel_launch(void* const* d_in, const int* in_sizes, int n_in,
                              void* d_out, int out_size, void* d_ws, size_t ws_size,
                              hipStream_t stream) {
    const float* x  = (const float*)d_in[0];
    const float* Wq = (const float*)d_in[1];
    const float* Wk = (const float*)d_in[2];
    const float* Wv = (const float*)d_in[3];
    const float* Wo = (const float*)d_in[4];
    const int* tpos = (const int*)d_in[5];
    float* out = (float*)d_out;

    char* ws = (char*)d_ws;
    unsigned short* xb   = (unsigned short*)(ws + 0);            // 8 MB (dead after QKV gemm)
    unsigned short* Wb   = (unsigned short*)(ws + (8u << 20));   // 8 MB (Wq,Wk,Wv,Wo bf16)
    unsigned short* QKV  = (unsigned short*)(ws + (16u << 20));  // 24 MB [S][3072]
    unsigned short* ctxb = (unsigned short*)(ws + (40u << 20));  // 8 MB
    float* costab = (float*)(ws + (48u << 20));                  // 1 MB [4096][64]
    float* sintab = (float*)(ws + (49u << 20));                  // 1 MB
    unsigned short* Vtb  = xb;   // reuse: written by vtrans after QKV gemm

    // prep: x->bf16 | weights->bf16 | extended RoPE tables
    prep_k<<<9216, 256, 0, stream>>>(x, Wq, Wk, Wv, Wo, tpos, xb, Wb, costab, sintab);

    // fused QKV projection with RoPE/scale epilogue: 768 blocks = 3/CU
    gemm_qkv_k<<<dim3(24, 32), 256, 0, stream>>>(xb, Wb, QKV, costab, sintab);

    // V transpose: QKV cols 2048.. -> Vt [1024][S]
    vtrans_k<<<dim3(S_LEN / 64, D_MODEL / 64), 256, 0, stream>>>(QKV + 2048, Vtb);

    // paired causal attention with phase-2 kv-split: 512 uniform blocks
    attn_k<<<dim3(N_HEADS, 32), 512, 0, stream>>>(QKV, QKV + 1024, Vtb, ctxb);

    // out projection, 64x128 tiles: 512 blocks = 2/CU
    gemm_o_k<<<dim3(8, 64), 256, 0, stream>>>(ctxb, Wb + 3u * 1024 * 1024, out);
}